// Round 8
// baseline (2553.317 us; speedup 1.0000x reference)
//
#include <hip/hip_runtime.h>
#include <hip/hip_bf16.h>
#include <math.h>

typedef __attribute__((ext_vector_type(8))) short short8;
typedef __attribute__((ext_vector_type(4))) float f32x4;

constexpr int nB = 64, nT = 512, nE = 768, nH = 128, nG = 512, nC = 18;
constexpr int nBT = nB * nT;

__device__ __forceinline__ float bf2f(unsigned short u) { return __uint_as_float(((unsigned int)u) << 16); }
__device__ __forceinline__ unsigned short f2bf(float f) {
  __hip_bfloat16 h = __float2bfloat16(f);
  return *reinterpret_cast<unsigned short*>(&h);
}
__device__ __forceinline__ float rlane(float v, int lane) {
  return __uint_as_float(__builtin_amdgcn_readlane(__float_as_uint(v), lane));
}
__device__ __forceinline__ float fast_sig(float x) {
  return __builtin_amdgcn_rcpf(1.0f + __builtin_amdgcn_exp2f(-1.44269504f * x));
}
__device__ __forceinline__ float fast_tanh(float x) {
  return 1.0f - 2.0f * __builtin_amdgcn_rcpf(1.0f + __builtin_amdgcn_exp2f(2.88539008f * x));
}
__device__ __forceinline__ float fast_exp(float x) { return __builtin_amdgcn_exp2f(1.44269504f * x); }
__device__ __forceinline__ float fast_log(float x) { return __builtin_amdgcn_logf(x) * 0.69314718f; }

// ---------------- f32 -> bf16 convert: both Wih weights in one launch ----------------
__global__ __launch_bounds__(256) void cvt_kernel(const float* __restrict__ inF,
                                                  const float* __restrict__ inB,
                                                  unsigned short* __restrict__ outF,
                                                  unsigned short* __restrict__ outB, int n8) {
  const int half = gridDim.x >> 1;
  const float* in = (blockIdx.x < half) ? inF : inB;
  unsigned short* out = (blockIdx.x < half) ? outF : outB;
  const int bid = (blockIdx.x < half) ? blockIdx.x : blockIdx.x - half;
  int i = bid * blockDim.x + threadIdx.x;
  const int stride = half * blockDim.x;
  for (; i < n8; i += stride) {
    const float4 a = ((const float4*)in)[(size_t)i * 2];
    const float4 b = ((const float4*)in)[(size_t)i * 2 + 1];
    unsigned short u[8] = {f2bf(a.x), f2bf(a.y), f2bf(a.z), f2bf(a.w),
                           f2bf(b.x), f2bf(b.y), f2bf(b.z), f2bf(b.w)};
    ((float4*)out)[i] = *(float4*)u;
  }
}

// ---------------- projection GEMM (bf16 MFMA): pre = x @ Wih^T + b ----------------
__global__ __launch_bounds__(256) void proj_kernel(
    const float* __restrict__ x,
    const unsigned short* __restrict__ wfb, const unsigned short* __restrict__ wbb,
    const float* __restrict__ biasF, const float* __restrict__ biasB,
    unsigned short* __restrict__ Pf, unsigned short* __restrict__ Pb)
{
  const int bid = blockIdx.x;
  const int mt = bid & 255, sub = bid >> 8;
  const int dir = sub >> 2, nt = sub & 3;
  const unsigned short* W = dir ? wbb : wfb;
  const float* bias = dir ? biasB : biasF;
  unsigned short* P = dir ? Pb : Pf;
  const int m0 = mt * 128, n0 = nt * 128;

  __shared__ unsigned short As[128 * 40];
  __shared__ unsigned short Bs[128 * 40];
  const int tid = threadIdx.x;
  const int w = tid >> 6, lane = tid & 63, l15 = lane & 15, l4 = lane >> 4;
  const int wr = w >> 1, wc = w & 1;
  const int srow = tid >> 1, shalf = tid & 1;

  const float* srcA = x + (size_t)(m0 + srow) * nE + shalf * 16;
  const unsigned short* srcB = W + (size_t)(n0 + srow) * nE + shalf * 16;

  f32x4 acc[4][4];
#pragma unroll
  for (int i = 0; i < 4; ++i)
#pragma unroll
    for (int j = 0; j < 4; ++j) acc[i][j] = (f32x4){0.f, 0.f, 0.f, 0.f};

  for (int k0 = 0; k0 < nE; k0 += 32) {
    const float4 a0 = *(const float4*)(srcA + k0);
    const float4 a1 = *(const float4*)(srcA + k0 + 4);
    const float4 a2 = *(const float4*)(srcA + k0 + 8);
    const float4 a3 = *(const float4*)(srcA + k0 + 12);
    const float4 b0 = *(const float4*)(srcB + k0);
    const float4 b1 = *(const float4*)(srcB + k0 + 8);
    unsigned short ua[16] = {f2bf(a0.x), f2bf(a0.y), f2bf(a0.z), f2bf(a0.w),
                             f2bf(a1.x), f2bf(a1.y), f2bf(a1.z), f2bf(a1.w),
                             f2bf(a2.x), f2bf(a2.y), f2bf(a2.z), f2bf(a2.w),
                             f2bf(a3.x), f2bf(a3.y), f2bf(a3.z), f2bf(a3.w)};
    __syncthreads();
    *(float4*)&As[srow * 40 + shalf * 16] = *(float4*)&ua[0];
    *(float4*)&As[srow * 40 + shalf * 16 + 8] = *(float4*)&ua[8];
    *(float4*)&Bs[srow * 40 + shalf * 16] = b0;
    *(float4*)&Bs[srow * 40 + shalf * 16 + 8] = b1;
    __syncthreads();
    short8 af[4], bfr[4];
#pragma unroll
    for (int i = 0; i < 4; ++i) af[i] = *(const short8*)&As[(wr * 64 + i * 16 + l15) * 40 + l4 * 8];
#pragma unroll
    for (int j = 0; j < 4; ++j) bfr[j] = *(const short8*)&Bs[(wc * 64 + j * 16 + l15) * 40 + l4 * 8];
#pragma unroll
    for (int i = 0; i < 4; ++i)
#pragma unroll
      for (int j = 0; j < 4; ++j)
        acc[i][j] = __builtin_amdgcn_mfma_f32_16x16x32_bf16(af[i], bfr[j], acc[i][j], 0, 0, 0);
  }
  float bv[4];
#pragma unroll
  for (int j = 0; j < 4; ++j) bv[j] = bias[n0 + wc * 64 + j * 16 + l15];
#pragma unroll
  for (int i = 0; i < 4; ++i) {
#pragma unroll
    for (int j = 0; j < 4; ++j) {
      const int col = n0 + wc * 64 + j * 16 + l15;
#pragma unroll
      for (int r = 0; r < 4; ++r) {
        const int row = m0 + wr * 64 + i * 16 + l4 * 4 + r;
        P[(size_t)row * nG + col] = f2bf(acc[i][j][r] + bv[j]);
      }
    }
  }
}

// ---------------- MFMA LSTM v5: 16 batches/block, full MFMA utilization ----------------
// 8 blocks = 4 groups x 2 dirs, 8 waves. Lane (l15,l4) of wave w:
//   batch = l15 (all 16 B-columns used), cells = w*16 + m*4 + l4 for m=0..3.
// C-layout row = l4*4+reg with gate' = cell*4+type  =>  acc[m][reg] = gate type `reg`
// of cell m -- activations fully register-local, no extraction selects.
__global__ __launch_bounds__(512, 1) void lstm_kernel(
    const unsigned short* __restrict__ Pf, const unsigned short* __restrict__ Pb,
    const float* __restrict__ WhhF, const float* __restrict__ WhhB,
    unsigned short* __restrict__ hf, unsigned short* __restrict__ hb)
{
  const int bid = blockIdx.x;
  const int dir = bid & 1, grp = bid >> 1;
  const int b0 = grp * 16;
  const unsigned short* pre = dir ? Pb : Pf;
  const float* Whh = dir ? WhhB : WhhF;
  unsigned short* hout = dir ? hb : hf;

  const int tid = threadIdx.x, w = tid >> 6, lane = tid & 63;
  const int l15 = lane & 15, l4 = lane >> 4;          // l15 = batch, l4 = cell sub
  const int swz = ((l15 & 7) << 4) | ((l15 >> 3) << 3);  // XOR bits 3-6 (keeps b128 contiguous)

  __shared__ unsigned short h_lds[2 * 16 * 128];      // 8 KB, double-buffered

  // A fragments: Whh rows permuted gate' = cell*4 + type; wave w owns rows w*64..w*64+63
  short8 Af[4][4];
#pragma unroll
  for (int m = 0; m < 4; ++m) {
    const int gp = w * 64 + m * 16 + l15;
    const int gorig = (gp & 3) * 128 + (gp >> 2);
#pragma unroll
    for (int kk = 0; kk < 4; ++kk) {
      const float* wp = Whh + (size_t)gorig * nH + kk * 32 + l4 * 8;
      const float4 v0 = *(const float4*)wp;
      const float4 v1 = *(const float4*)(wp + 4);
      unsigned short u[8] = {f2bf(v0.x), f2bf(v0.y), f2bf(v0.z), f2bf(v0.w),
                             f2bf(v1.x), f2bf(v1.y), f2bf(v1.z), f2bf(v1.w)};
      Af[m][kk] = *(short8*)u;
    }
  }
  for (int i = tid; i < 2 * 16 * 128; i += 512) h_lds[i] = 0;

  float c_state[4] = {0.f, 0.f, 0.f, 0.f};
  // lane's pre slice: batch b0+l15; gate addr = t*nG + type*128 + cell
  const unsigned short* pb_ = pre + (size_t)(b0 + l15) * nT * nG;
  const int coff = w * 16 + l4;  // + m*4 gives the cell

  unsigned short pA[16], pB[16];
  {
    const int tt0 = dir ? (nT - 1) : 0;
    const int tt1 = dir ? (nT - 2) : 1;
#pragma unroll
    for (int m = 0; m < 4; ++m)
#pragma unroll
      for (int ty = 0; ty < 4; ++ty) {
        pA[m * 4 + ty] = pb_[(size_t)tt0 * nG + ty * 128 + coff + m * 4];
        pB[m * 4 + ty] = pb_[(size_t)tt1 * nG + ty * 128 + coff + m * 4];
      }
  }
  __syncthreads();

#define LSTM_STEP(RB, T, BUFC)                                                    \
  {                                                                               \
    const int ttime = dir ? (nT - 1 - (T)) : (T);                                 \
    short8 bfr[4];                                                                \
    _Pragma("unroll")                                                             \
    for (int kk = 0; kk < 4; ++kk) {                                              \
      const int idx = (RB) * 2048 + l15 * 128 + ((kk * 32 + l4 * 8) ^ swz);       \
      bfr[kk] = *(const short8*)&h_lds[idx];                                      \
    }                                                                             \
    f32x4 acc[4];                                                                 \
    _Pragma("unroll")                                                             \
    for (int m = 0; m < 4; ++m) {                                                 \
      acc[m][0] = bf2f(BUFC[m * 4 + 0]);                                          \
      acc[m][1] = bf2f(BUFC[m * 4 + 1]);                                          \
      acc[m][2] = bf2f(BUFC[m * 4 + 2]);                                          \
      acc[m][3] = bf2f(BUFC[m * 4 + 3]);                                          \
    }                                                                             \
    {                                                                             \
      const int tl = ((T) + 2 < nT) ? (T) + 2 : (T);                              \
      const int ttl = dir ? (nT - 1 - tl) : tl;                                   \
      _Pragma("unroll")                                                           \
      for (int m = 0; m < 4; ++m)                                                 \
        _Pragma("unroll")                                                         \
        for (int ty = 0; ty < 4; ++ty)                                            \
          BUFC[m * 4 + ty] = pb_[(size_t)ttl * nG + ty * 128 + coff + m * 4];     \
    }                                                                             \
    _Pragma("unroll")                                                             \
    for (int kk = 0; kk < 4; ++kk)                                                \
      _Pragma("unroll")                                                           \
      for (int m = 0; m < 4; ++m)                                                 \
        acc[m] = __builtin_amdgcn_mfma_f32_16x16x32_bf16(Af[m][kk], bfr[kk], acc[m], 0, 0, 0); \
    _Pragma("unroll")                                                             \
    for (int m = 0; m < 4; ++m) {                                                 \
      const float gi = acc[m][0], gf = acc[m][1], gg = acc[m][2], go = acc[m][3]; \
      c_state[m] = fast_sig(gf) * c_state[m] + fast_sig(gi) * fast_tanh(gg);      \
      const float hval = fast_sig(go) * fast_tanh(c_state[m]);                    \
      const unsigned short hu = f2bf(hval);                                       \
      const int cellm = coff + m * 4;                                             \
      h_lds[((RB) ^ 1) * 2048 + l15 * 128 + (cellm ^ swz)] = hu;                  \
      hout[((size_t)(b0 + l15) * nT + ttime) * nH + cellm] = hu;                  \
    }                                                                             \
    asm volatile("s_waitcnt lgkmcnt(0)" ::: "memory");                            \
    __builtin_amdgcn_sched_barrier(0);                                            \
    __builtin_amdgcn_s_barrier();                                                 \
  }

  for (int t2 = 0; t2 < nT; t2 += 2) {
    LSTM_STEP(0, t2, pA)
    LSTM_STEP(1, t2 + 1, pB)
  }
#undef LSTM_STEP
}

// ---------------- emissions: em = [hf|hb] @ Wfc^T + bfc ----------------
__global__ __launch_bounds__(256) void em_kernel(
    const unsigned short* __restrict__ hf, const unsigned short* __restrict__ hb,
    const float* __restrict__ Wfc, const float* __restrict__ bfc,
    float* __restrict__ em)
{
  __shared__ float seq[32][260];
  __shared__ float Wf[18][260];
  const int tid = threadIdx.x;
  const int row0 = blockIdx.x * 32;
  for (int i = tid; i < 32 * 32; i += 256) {
    const int r = i >> 5, seg = i & 31;
    const unsigned short* src = (seg < 16) ? (hf + (size_t)(row0 + r) * nH + seg * 8)
                                           : (hb + (size_t)(row0 + r) * nH + (seg - 16) * 8);
    const float4 v = *(const float4*)src;
    const unsigned short* u = (const unsigned short*)&v;
#pragma unroll
    for (int k = 0; k < 8; ++k) seq[r][seg * 8 + k] = bf2f(u[k]);
  }
  for (int i = tid; i < nC * 256; i += 256) {
    const int cc = i >> 8, k = i & 255;
    Wf[cc][k] = Wfc[cc * 256 + k];
  }
  __syncthreads();
  for (int o = tid; o < 32 * nC; o += 256) {
    const int r = o / nC, cc = o - r * nC;
    float acc = bfc[cc];
    const float4* s4 = (const float4*)&seq[r][0];
    const float4* w4 = (const float4*)&Wf[cc][0];
#pragma unroll
    for (int q = 0; q < 64; ++q) {
      const float4 a = s4[q]; const float4 wv = w4[q];
      acc += a.x * wv.x + a.y * wv.y + a.z * wv.z + a.w * wv.w;
    }
    em[(size_t)(row0 + r) * nC + cc] = acc;
  }
}

// ---------------- fused CRF + Viterbi (register recurrences) ----------------
__global__ __launch_bounds__(128) void crfvit_kernel(
    const float* __restrict__ em, const int* __restrict__ labels,
    const int* __restrict__ mask, const float* __restrict__ start,
    const float* __restrict__ endt, const float* __restrict__ trans,
    float* __restrict__ llh, float* __restrict__ out_path)
{
  const int b = blockIdx.x; const int tid = threadIdx.x;
  __shared__ float tr[nC * nC];
  __shared__ unsigned char bp[(nT - 1) * nC];
  __shared__ unsigned char path[nT];
  for (int i = tid; i < nC * nC; i += 128) tr[i] = trans[i];
  __syncthreads();
  const float* eb = em + (size_t)b * nT * nC;

#define MAX18(c) fmaxf(fmaxf(fmaxf(fmaxf(fmaxf(c[0], c[1]), c[2]), fmaxf(fmaxf(c[3], c[4]), c[5])),           \
                             fmaxf(fmaxf(fmaxf(c[6], c[7]), c[8]), fmaxf(fmaxf(c[9], c[10]), c[11]))),        \
                       fmaxf(fmaxf(fmaxf(c[12], c[13]), c[14]), fmaxf(fmaxf(c[15], c[16]), c[17])))

  if (tid < 64) {
    const int l = tid;
    const int lc = l < nC ? l : nC - 1;
    const int* tg = labels + (size_t)b * nT;
    const int* mk = mask + (size_t)b * nT;

    float np = 0.f; int cnt = 0;
    for (int t = l; t < nT; t += 64) {
      const int tag = tg[t];
      const float e = eb[(size_t)t * nC + tag];
      if (t == 0) np += start[tag] + e;
      else np += (float)mk[t] * (e + tr[tg[t - 1] * nC + tag]);
      cnt += mk[t];
    }
#pragma unroll
    for (int off = 32; off; off >>= 1) { np += __shfl_xor(np, off); cnt += __shfl_xor(cnt, off); }
    const float num = np + endt[tg[cnt - 1]];

    float trc[nC];
#pragma unroll
    for (int i = 0; i < nC; ++i) trc[i] = tr[i * nC + lc];

    float alpha_r = start[lc] + eb[lc];
    float eA = eb[1 * nC + lc];
    float eB = eb[2 * nC + lc];
    float eC = eb[3 * nC + lc];
    for (int tk = 0; tk < 8; ++tk) {
      const unsigned long long mb = __ballot(mk[tk * 64 + l] != 0);
      for (int tt = (tk == 0 ? 1 : 0); tt < 64; ++tt) {
        const int t = tk * 64 + tt;
        const float ecur = eA; eA = eB; eB = eC;
        const int tl = t + 3 < nT ? t + 3 : nT - 1;
        eC = eb[(size_t)tl * nC + lc];
        float cand[nC];
#pragma unroll
        for (int i = 0; i < nC; ++i) cand[i] = rlane(alpha_r, i) + trc[i];
        const float m = MAX18(cand);
        float ex[nC];
#pragma unroll
        for (int i = 0; i < nC; ++i) ex[i] = fast_exp(cand[i] - m);
        float s = 0.f;
#pragma unroll
        for (int i = 0; i < nC; ++i) s += ex[i];
        const float anew = m + fast_log(s) + ecur;
        alpha_r = ((mb >> tt) & 1) ? anew : alpha_r;
      }
    }
    const float v = (l < nC) ? (alpha_r + endt[l]) : -3.0e38f;
    float m = v;
#pragma unroll
    for (int off = 32; off; off >>= 1) m = fmaxf(m, __shfl_xor(m, off));
    float s = (l < nC) ? fast_exp(v - m) : 0.f;
#pragma unroll
    for (int off = 32; off; off >>= 1) s += __shfl_xor(s, off);
    if (l == 0) llh[b] = num - (m + fast_log(s));
  } else {
    const int l = tid - 64;
    const int lc = l < nC ? l : nC - 1;
    float trc[nC];
#pragma unroll
    for (int i = 0; i < nC; ++i) trc[i] = tr[i * nC + lc];

    float score_r = start[lc] + eb[lc];
    float eA = eb[1 * nC + lc];
    float eB = eb[2 * nC + lc];
    float eC = eb[3 * nC + lc];
    for (int t = 1; t < nT; ++t) {
      const float ecur = eA; eA = eB; eB = eC;
      const int tl = t + 3 < nT ? t + 3 : nT - 1;
      eC = eb[(size_t)tl * nC + lc];
      float cand[nC];
#pragma unroll
      for (int i = 0; i < nC; ++i) cand[i] = rlane(score_r, i) + trc[i];
      const float m = MAX18(cand);
      int sel[nC];
#pragma unroll
      for (int i = 0; i < nC; ++i) sel[i] = (cand[i] == m) ? i : 63;
      int arg = sel[0];
#pragma unroll
      for (int i = 1; i < nC; ++i) arg = min(arg, sel[i]);
      score_r = m + ecur;
      if (l < nC) bp[(t - 1) * nC + l] = (unsigned char)arg;
    }
    if (l == 0) {
      float mm = -3.0e38f; int last = 0;
      for (int i = 0; i < nC; ++i) {
        const float v = rlane(score_r, i) + endt[i];
        if (v > mm) { mm = v; last = i; }
      }
      path[nT - 1] = (unsigned char)last;
      int cur = last;
      for (int t = nT - 2; t >= 0; --t) { cur = bp[t * nC + cur]; path[t] = (unsigned char)cur; }
    }
    asm volatile("s_waitcnt lgkmcnt(0)" ::: "memory");
    __builtin_amdgcn_wave_barrier();
    for (int t = l; t < nT; t += 64) out_path[(size_t)b * nT + t] = (float)(path[t] + 1);
  }
#undef MAX18
}

// ---------------- loss finalize ----------------
__global__ __launch_bounds__(64) void loss_kernel(const float* __restrict__ llh, float* __restrict__ out)
{
  const int l = threadIdx.x;
  float v = llh[l];
#pragma unroll
  for (int off = 32; off; off >>= 1) v += __shfl_xor(v, off);
  if (l == 0) out[0] = -v / (float)nB;
}

extern "C" void kernel_launch(void* const* d_in, const int* in_sizes, int n_in,
                              void* d_out, int out_size, void* d_ws, size_t ws_size,
                              hipStream_t stream)
{
  const float* x      = (const float*)d_in[0];
  const int*   amask  = (const int*)d_in[1];
  const int*   labels = (const int*)d_in[2];
  const float* Wih_f  = (const float*)d_in[3];
  const float* Whh_f  = (const float*)d_in[4];
  const float* b_f    = (const float*)d_in[5];
  const float* Wih_b  = (const float*)d_in[6];
  const float* Whh_b  = (const float*)d_in[7];
  const float* b_b    = (const float*)d_in[8];
  const float* Wfc    = (const float*)d_in[9];
  const float* bfc    = (const float*)d_in[10];
  const float* start  = (const float*)d_in[11];
  const float* endt   = (const float*)d_in[12];
  const float* trans  = (const float*)d_in[13];

  float* out = (float*)d_out;
  float* ws = (float*)d_ws;
  unsigned short* preF = (unsigned short*)ws;                       // 16.7M bf16
  unsigned short* preB = preF + (size_t)nBT * nG;                   // 16.7M bf16
  unsigned short* hf   = preB + (size_t)nBT * nG;                   // 4.2M bf16
  unsigned short* hb   = hf + (size_t)nBT * nH;                     // 4.2M bf16
  float* em  = (float*)(hb + (size_t)nBT * nH);                     // 590K f32
  float* llh = em + (size_t)nBT * nC;                               // 64 f32
  unsigned short* wfb = (unsigned short*)(llh + 64);                // 393K bf16
  unsigned short* wbb = wfb + (size_t)nG * nE;                      // 393K bf16

  cvt_kernel<<<384, 256, 0, stream>>>(Wih_f, Wih_b, wfb, wbb, nG * nE / 8);
  proj_kernel<<<2048, 256, 0, stream>>>(x, wfb, wbb, b_f, b_b, preF, preB);
  lstm_kernel<<<8, 512, 0, stream>>>(preF, preB, Whh_f, Whh_b, hf, hb);
  em_kernel<<<1024, 256, 0, stream>>>(hf, hb, Wfc, bfc, em);
  crfvit_kernel<<<64, 128, 0, stream>>>(em, labels, amask, start, endt, trans, llh, out);
  loss_kernel<<<1, 64, 0, stream>>>(llh, out + nBT);
}

// Round 9
// 935.262 us; speedup vs baseline: 2.7301x; 2.7301x over previous
//
#include <hip/hip_runtime.h>
#include <hip/hip_bf16.h>
#include <math.h>

typedef __attribute__((ext_vector_type(8))) short short8;
typedef __attribute__((ext_vector_type(4))) float f32x4;
typedef __attribute__((ext_vector_type(4))) unsigned short us4;

constexpr int nB = 64, nT = 512, nE = 768, nH = 128, nG = 512, nC = 18;
constexpr int nBT = nB * nT;

__device__ __forceinline__ float bf2f(unsigned short u) { return __uint_as_float(((unsigned int)u) << 16); }
__device__ __forceinline__ unsigned short f2bf(float f) {
  __hip_bfloat16 h = __float2bfloat16(f);
  return *reinterpret_cast<unsigned short*>(&h);
}
__device__ __forceinline__ float rlane(float v, int lane) {
  return __uint_as_float(__builtin_amdgcn_readlane(__float_as_uint(v), lane));
}
__device__ __forceinline__ float fast_sig(float x) {
  return __builtin_amdgcn_rcpf(1.0f + __builtin_amdgcn_exp2f(-1.44269504f * x));
}
__device__ __forceinline__ float fast_tanh(float x) {
  return 1.0f - 2.0f * __builtin_amdgcn_rcpf(1.0f + __builtin_amdgcn_exp2f(2.88539008f * x));
}
__device__ __forceinline__ float fast_exp(float x) { return __builtin_amdgcn_exp2f(1.44269504f * x); }
__device__ __forceinline__ float fast_log(float x) { return __builtin_amdgcn_logf(x) * 0.69314718f; }

// ---------------- f32 -> bf16 convert: both Wih weights in one launch ----------------
__global__ __launch_bounds__(256) void cvt_kernel(const float* __restrict__ inF,
                                                  const float* __restrict__ inB,
                                                  unsigned short* __restrict__ outF,
                                                  unsigned short* __restrict__ outB, int n8) {
  const int half = gridDim.x >> 1;
  const float* in = (blockIdx.x < half) ? inF : inB;
  unsigned short* out = (blockIdx.x < half) ? outF : outB;
  const int bid = (blockIdx.x < half) ? blockIdx.x : blockIdx.x - half;
  int i = bid * blockDim.x + threadIdx.x;
  const int stride = half * blockDim.x;
  for (; i < n8; i += stride) {
    const float4 a = ((const float4*)in)[(size_t)i * 2];
    const float4 b = ((const float4*)in)[(size_t)i * 2 + 1];
    unsigned short u[8] = {f2bf(a.x), f2bf(a.y), f2bf(a.z), f2bf(a.w),
                           f2bf(b.x), f2bf(b.y), f2bf(b.z), f2bf(b.w)};
    ((float4*)out)[i] = *(float4*)u;
  }
}

// ---------------- projection GEMM -> packed preP layout ----------------
// preP[t][grp][cell][bl][ty]: addr = t*32768 + grp*8192 + cell*64 + bl*4 + ty
//   (grp = b>>4, bl = b&15, gate' = cell*4+ty, orig gate = ty*128+cell)
// Tile: rows = 16 batches x 8 timesteps (row128 = bl*8 + tloc), cols = 128 gate'-contig.
// B-staging reads W rows through the gate' permutation; math identical to plain GEMM.
__global__ __launch_bounds__(256) void proj_kernel(
    const float* __restrict__ x,
    const unsigned short* __restrict__ wfb, const unsigned short* __restrict__ wbb,
    const float* __restrict__ biasF, const float* __restrict__ biasB,
    unsigned short* __restrict__ Pf, unsigned short* __restrict__ Pb)
{
  const int bid = blockIdx.x;
  const int mt = bid & 255, sub = bid >> 8;
  const int dir = sub >> 2, nt = sub & 3;
  const unsigned short* W = dir ? wbb : wfb;
  const float* bias = dir ? biasB : biasF;
  unsigned short* P = dir ? Pb : Pf;
  const int grp = mt >> 6, t0 = (mt & 63) * 8;
  const int n0 = nt * 128;  // gate'-space column offset

  __shared__ unsigned short As[128 * 40];
  __shared__ unsigned short Bs[128 * 40];
  const int tid = threadIdx.x;
  const int w = tid >> 6, lane = tid & 63, l15 = lane & 15, l4 = lane >> 4;
  const int wr = w >> 1, wc = w & 1;
  const int srow = tid >> 1, shalf = tid & 1;

  // A row srow -> batch grp*16 + (srow>>3), time t0 + (srow&7)
  const float* srcA = x + ((size_t)(grp * 16 + (srow >> 3)) * nT + t0 + (srow & 7)) * nE + shalf * 16;
  // B row srow -> gate' = n0+srow -> orig gate row
  const int gprime = n0 + srow;
  const int gorig = ((gprime & 3) << 7) | (gprime >> 2);
  const unsigned short* srcB = W + (size_t)gorig * nE + shalf * 16;

  f32x4 acc[4][4];
#pragma unroll
  for (int i = 0; i < 4; ++i)
#pragma unroll
    for (int j = 0; j < 4; ++j) acc[i][j] = (f32x4){0.f, 0.f, 0.f, 0.f};

  for (int k0 = 0; k0 < nE; k0 += 32) {
    const float4 a0 = *(const float4*)(srcA + k0);
    const float4 a1 = *(const float4*)(srcA + k0 + 4);
    const float4 a2 = *(const float4*)(srcA + k0 + 8);
    const float4 a3 = *(const float4*)(srcA + k0 + 12);
    const float4 b0 = *(const float4*)(srcB + k0);
    const float4 b1 = *(const float4*)(srcB + k0 + 8);
    unsigned short ua[16] = {f2bf(a0.x), f2bf(a0.y), f2bf(a0.z), f2bf(a0.w),
                             f2bf(a1.x), f2bf(a1.y), f2bf(a1.z), f2bf(a1.w),
                             f2bf(a2.x), f2bf(a2.y), f2bf(a2.z), f2bf(a2.w),
                             f2bf(a3.x), f2bf(a3.y), f2bf(a3.z), f2bf(a3.w)};
    __syncthreads();
    *(float4*)&As[srow * 40 + shalf * 16] = *(float4*)&ua[0];
    *(float4*)&As[srow * 40 + shalf * 16 + 8] = *(float4*)&ua[8];
    *(float4*)&Bs[srow * 40 + shalf * 16] = b0;
    *(float4*)&Bs[srow * 40 + shalf * 16 + 8] = b1;
    __syncthreads();
    short8 af[4], bfr[4];
#pragma unroll
    for (int i = 0; i < 4; ++i) af[i] = *(const short8*)&As[(wr * 64 + i * 16 + l15) * 40 + l4 * 8];
#pragma unroll
    for (int j = 0; j < 4; ++j) bfr[j] = *(const short8*)&Bs[(wc * 64 + j * 16 + l15) * 40 + l4 * 8];
#pragma unroll
    for (int i = 0; i < 4; ++i)
#pragma unroll
      for (int j = 0; j < 4; ++j)
        acc[i][j] = __builtin_amdgcn_mfma_f32_16x16x32_bf16(af[i], bfr[j], acc[i][j], 0, 0, 0);
  }
  // bias indexed via gate' -> orig
  float bv[4];
  int cellj[4], tyj[4];
#pragma unroll
  for (int j = 0; j < 4; ++j) {
    const int colp = n0 + wc * 64 + j * 16 + l15;
    cellj[j] = colp >> 2; tyj[j] = colp & 3;
    bv[j] = bias[(tyj[j] << 7) | cellj[j]];
  }
#pragma unroll
  for (int i = 0; i < 4; ++i) {
#pragma unroll
    for (int r = 0; r < 4; ++r) {
      const int row128 = wr * 64 + i * 16 + l4 * 4 + r;
      const int bl = row128 >> 3, tloc = row128 & 7;
      const size_t base = (size_t)(t0 + tloc) * 32768 + (size_t)grp * 8192 + bl * 4;
#pragma unroll
      for (int j = 0; j < 4; ++j)
        P[base + (size_t)cellj[j] * 64 + tyj[j]] = f2bf(acc[i][j][r] + bv[j]);
    }
  }
}

// ---------------- MFMA LSTM v6: 16 batches/block + packed coalesced pre loads ----------
// 8 blocks = 4 grps x 2 dirs, 8 waves. Lane (l15,l4) of wave w: batch = l15,
// cells = w*16 + m*4 + l4. acc[m][ty] = gate type ty of cell m (register-local).
// pre loads: one ushort4 per (m); whole wave = contiguous 512B.
__global__ __launch_bounds__(512, 1) void lstm_kernel(
    const unsigned short* __restrict__ Pf, const unsigned short* __restrict__ Pb,
    const float* __restrict__ WhhF, const float* __restrict__ WhhB,
    unsigned short* __restrict__ hf, unsigned short* __restrict__ hb)
{
  const int bid = blockIdx.x;
  const int dir = bid & 1, grp = bid >> 1;
  const int b0 = grp * 16;
  const unsigned short* pre = dir ? Pb : Pf;
  const float* Whh = dir ? WhhB : WhhF;
  unsigned short* hout = dir ? hb : hf;

  const int tid = threadIdx.x, w = tid >> 6, lane = tid & 63;
  const int l15 = lane & 15, l4 = lane >> 4;          // l15 = batch, l4 = cell sub
  const int swz = ((l15 & 7) << 4) | ((l15 >> 3) << 3);

  __shared__ unsigned short h_lds[2 * 16 * 128];      // 8 KB double-buffered

  short8 Af[4][4];
#pragma unroll
  for (int m = 0; m < 4; ++m) {
    const int gp = w * 64 + m * 16 + l15;
    const int gorig = (gp & 3) * 128 + (gp >> 2);
#pragma unroll
    for (int kk = 0; kk < 4; ++kk) {
      const float* wp = Whh + (size_t)gorig * nH + kk * 32 + l4 * 8;
      const float4 v0 = *(const float4*)wp;
      const float4 v1 = *(const float4*)(wp + 4);
      unsigned short u[8] = {f2bf(v0.x), f2bf(v0.y), f2bf(v0.z), f2bf(v0.w),
                             f2bf(v1.x), f2bf(v1.y), f2bf(v1.z), f2bf(v1.w)};
      Af[m][kk] = *(short8*)u;
    }
  }
  for (int i = tid; i < 2 * 16 * 128; i += 512) h_lds[i] = 0;

  float c_state[4] = {0.f, 0.f, 0.f, 0.f};
  // packed pre: lane-const base; per (t,m) offset = t*32768 + m*256
  const unsigned short* pbase = pre + (size_t)grp * 8192 + (w * 16 + l4) * 64 + l15 * 4;
  const int coff = w * 16 + l4;

  unsigned short pA[16], pB[16];
  {
    const int tt0 = dir ? (nT - 1) : 0;
    const int tt1 = dir ? (nT - 2) : 1;
#pragma unroll
    for (int m = 0; m < 4; ++m) {
      *(us4*)&pA[m * 4] = *(const us4*)(pbase + (size_t)tt0 * 32768 + m * 256);
      *(us4*)&pB[m * 4] = *(const us4*)(pbase + (size_t)tt1 * 32768 + m * 256);
    }
  }
  __syncthreads();

#define LSTM_STEP(RB, T, BUFC)                                                    \
  {                                                                               \
    const int ttime = dir ? (nT - 1 - (T)) : (T);                                 \
    short8 bfr[4];                                                                \
    _Pragma("unroll")                                                             \
    for (int kk = 0; kk < 4; ++kk) {                                              \
      const int idx = (RB) * 2048 + l15 * 128 + ((kk * 32 + l4 * 8) ^ swz);       \
      bfr[kk] = *(const short8*)&h_lds[idx];                                      \
    }                                                                             \
    f32x4 acc[4];                                                                 \
    _Pragma("unroll")                                                             \
    for (int m = 0; m < 4; ++m) {                                                 \
      acc[m][0] = bf2f(BUFC[m * 4 + 0]);                                          \
      acc[m][1] = bf2f(BUFC[m * 4 + 1]);                                          \
      acc[m][2] = bf2f(BUFC[m * 4 + 2]);                                          \
      acc[m][3] = bf2f(BUFC[m * 4 + 3]);                                          \
    }                                                                             \
    {                                                                             \
      const int tl = ((T) + 2 < nT) ? (T) + 2 : (T);                              \
      const int ttl = dir ? (nT - 1 - tl) : tl;                                   \
      _Pragma("unroll")                                                           \
      for (int m = 0; m < 4; ++m)                                                 \
        *(us4*)&BUFC[m * 4] = *(const us4*)(pbase + (size_t)ttl * 32768 + m * 256); \
    }                                                                             \
    _Pragma("unroll")                                                             \
    for (int kk = 0; kk < 4; ++kk)                                                \
      _Pragma("unroll")                                                           \
      for (int m = 0; m < 4; ++m)                                                 \
        acc[m] = __builtin_amdgcn_mfma_f32_16x16x32_bf16(Af[m][kk], bfr[kk], acc[m], 0, 0, 0); \
    _Pragma("unroll")                                                             \
    for (int m = 0; m < 4; ++m) {                                                 \
      const float gi = acc[m][0], gf = acc[m][1], gg = acc[m][2], go = acc[m][3]; \
      c_state[m] = fast_sig(gf) * c_state[m] + fast_sig(gi) * fast_tanh(gg);      \
      const float hval = fast_sig(go) * fast_tanh(c_state[m]);                    \
      const unsigned short hu = f2bf(hval);                                       \
      const int cellm = coff + m * 4;                                             \
      h_lds[((RB) ^ 1) * 2048 + l15 * 128 + (cellm ^ swz)] = hu;                  \
      hout[((size_t)(b0 + l15) * nT + ttime) * nH + cellm] = hu;                  \
    }                                                                             \
    asm volatile("s_waitcnt lgkmcnt(0)" ::: "memory");                            \
    __builtin_amdgcn_sched_barrier(0);                                            \
    __builtin_amdgcn_s_barrier();                                                 \
  }

  for (int t2 = 0; t2 < nT; t2 += 2) {
    LSTM_STEP(0, t2, pA)
    LSTM_STEP(1, t2 + 1, pB)
  }
#undef LSTM_STEP
}

// ---------------- emissions: em = [hf|hb] @ Wfc^T + bfc ----------------
__global__ __launch_bounds__(256) void em_kernel(
    const unsigned short* __restrict__ hf, const unsigned short* __restrict__ hb,
    const float* __restrict__ Wfc, const float* __restrict__ bfc,
    float* __restrict__ em)
{
  __shared__ float seq[32][260];
  __shared__ float Wf[18][260];
  const int tid = threadIdx.x;
  const int row0 = blockIdx.x * 32;
  for (int i = tid; i < 32 * 32; i += 256) {
    const int r = i >> 5, seg = i & 31;
    const unsigned short* src = (seg < 16) ? (hf + (size_t)(row0 + r) * nH + seg * 8)
                                           : (hb + (size_t)(row0 + r) * nH + (seg - 16) * 8);
    const float4 v = *(const float4*)src;
    const unsigned short* u = (const unsigned short*)&v;
#pragma unroll
    for (int k = 0; k < 8; ++k) seq[r][seg * 8 + k] = bf2f(u[k]);
  }
  for (int i = tid; i < nC * 256; i += 256) {
    const int cc = i >> 8, k = i & 255;
    Wf[cc][k] = Wfc[cc * 256 + k];
  }
  __syncthreads();
  for (int o = tid; o < 32 * nC; o += 256) {
    const int r = o / nC, cc = o - r * nC;
    float acc = bfc[cc];
    const float4* s4 = (const float4*)&seq[r][0];
    const float4* w4 = (const float4*)&Wf[cc][0];
#pragma unroll
    for (int q = 0; q < 64; ++q) {
      const float4 a = s4[q]; const float4 wv = w4[q];
      acc += a.x * wv.x + a.y * wv.y + a.z * wv.z + a.w * wv.w;
    }
    em[(size_t)(row0 + r) * nC + cc] = acc;
  }
}

// ---------------- fused CRF + Viterbi (register recurrences) ----------------
__global__ __launch_bounds__(128) void crfvit_kernel(
    const float* __restrict__ em, const int* __restrict__ labels,
    const int* __restrict__ mask, const float* __restrict__ start,
    const float* __restrict__ endt, const float* __restrict__ trans,
    float* __restrict__ llh, float* __restrict__ out_path)
{
  const int b = blockIdx.x; const int tid = threadIdx.x;
  __shared__ float tr[nC * nC];
  __shared__ unsigned char bp[(nT - 1) * nC];
  __shared__ unsigned char path[nT];
  for (int i = tid; i < nC * nC; i += 128) tr[i] = trans[i];
  __syncthreads();
  const float* eb = em + (size_t)b * nT * nC;

#define MAX18(c) fmaxf(fmaxf(fmaxf(fmaxf(fmaxf(c[0], c[1]), c[2]), fmaxf(fmaxf(c[3], c[4]), c[5])),           \
                             fmaxf(fmaxf(fmaxf(c[6], c[7]), c[8]), fmaxf(fmaxf(c[9], c[10]), c[11]))),        \
                       fmaxf(fmaxf(fmaxf(c[12], c[13]), c[14]), fmaxf(fmaxf(c[15], c[16]), c[17])))

  if (tid < 64) {
    const int l = tid;
    const int lc = l < nC ? l : nC - 1;
    const int* tg = labels + (size_t)b * nT;
    const int* mk = mask + (size_t)b * nT;

    float np = 0.f; int cnt = 0;
    for (int t = l; t < nT; t += 64) {
      const int tag = tg[t];
      const float e = eb[(size_t)t * nC + tag];
      if (t == 0) np += start[tag] + e;
      else np += (float)mk[t] * (e + tr[tg[t - 1] * nC + tag]);
      cnt += mk[t];
    }
#pragma unroll
    for (int off = 32; off; off >>= 1) { np += __shfl_xor(np, off); cnt += __shfl_xor(cnt, off); }
    const float num = np + endt[tg[cnt - 1]];

    float trc[nC];
#pragma unroll
    for (int i = 0; i < nC; ++i) trc[i] = tr[i * nC + lc];

    float alpha_r = start[lc] + eb[lc];
    float eA = eb[1 * nC + lc];
    float eB = eb[2 * nC + lc];
    float eC = eb[3 * nC + lc];
    for (int tk = 0; tk < 8; ++tk) {
      const unsigned long long mb = __ballot(mk[tk * 64 + l] != 0);
      for (int tt = (tk == 0 ? 1 : 0); tt < 64; ++tt) {
        const int t = tk * 64 + tt;
        const float ecur = eA; eA = eB; eB = eC;
        const int tl = t + 3 < nT ? t + 3 : nT - 1;
        eC = eb[(size_t)tl * nC + lc];
        float cand[nC];
#pragma unroll
        for (int i = 0; i < nC; ++i) cand[i] = rlane(alpha_r, i) + trc[i];
        const float m = MAX18(cand);
        float ex[nC];
#pragma unroll
        for (int i = 0; i < nC; ++i) ex[i] = fast_exp(cand[i] - m);
        float s = 0.f;
#pragma unroll
        for (int i = 0; i < nC; ++i) s += ex[i];
        const float anew = m + fast_log(s) + ecur;
        alpha_r = ((mb >> tt) & 1) ? anew : alpha_r;
      }
    }
    const float v = (l < nC) ? (alpha_r + endt[l]) : -3.0e38f;
    float m = v;
#pragma unroll
    for (int off = 32; off; off >>= 1) m = fmaxf(m, __shfl_xor(m, off));
    float s = (l < nC) ? fast_exp(v - m) : 0.f;
#pragma unroll
    for (int off = 32; off; off >>= 1) s += __shfl_xor(s, off);
    if (l == 0) llh[b] = num - (m + fast_log(s));
  } else {
    const int l = tid - 64;
    const int lc = l < nC ? l : nC - 1;
    float trc[nC];
#pragma unroll
    for (int i = 0; i < nC; ++i) trc[i] = tr[i * nC + lc];

    float score_r = start[lc] + eb[lc];
    float eA = eb[1 * nC + lc];
    float eB = eb[2 * nC + lc];
    float eC = eb[3 * nC + lc];
    for (int t = 1; t < nT; ++t) {
      const float ecur = eA; eA = eB; eB = eC;
      const int tl = t + 3 < nT ? t + 3 : nT - 1;
      eC = eb[(size_t)tl * nC + lc];
      float cand[nC];
#pragma unroll
      for (int i = 0; i < nC; ++i) cand[i] = rlane(score_r, i) + trc[i];
      const float m = MAX18(cand);
      int sel[nC];
#pragma unroll
      for (int i = 0; i < nC; ++i) sel[i] = (cand[i] == m) ? i : 63;
      int arg = sel[0];
#pragma unroll
      for (int i = 1; i < nC; ++i) arg = min(arg, sel[i]);
      score_r = m + ecur;
      if (l < nC) bp[(t - 1) * nC + l] = (unsigned char)arg;
    }
    if (l == 0) {
      float mm = -3.0e38f; int last = 0;
      for (int i = 0; i < nC; ++i) {
        const float v = rlane(score_r, i) + endt[i];
        if (v > mm) { mm = v; last = i; }
      }
      path[nT - 1] = (unsigned char)last;
      int cur = last;
      for (int t = nT - 2; t >= 0; --t) { cur = bp[t * nC + cur]; path[t] = (unsigned char)cur; }
    }
    asm volatile("s_waitcnt lgkmcnt(0)" ::: "memory");
    __builtin_amdgcn_wave_barrier();
    for (int t = l; t < nT; t += 64) out_path[(size_t)b * nT + t] = (float)(path[t] + 1);
  }
#undef MAX18
}

// ---------------- loss finalize ----------------
__global__ __launch_bounds__(64) void loss_kernel(const float* __restrict__ llh, float* __restrict__ out)
{
  const int l = threadIdx.x;
  float v = llh[l];
#pragma unroll
  for (int off = 32; off; off >>= 1) v += __shfl_xor(v, off);
  if (l == 0) out[0] = -v / (float)nB;
}

extern "C" void kernel_launch(void* const* d_in, const int* in_sizes, int n_in,
                              void* d_out, int out_size, void* d_ws, size_t ws_size,
                              hipStream_t stream)
{
  const float* x      = (const float*)d_in[0];
  const int*   amask  = (const int*)d_in[1];
  const int*   labels = (const int*)d_in[2];
  const float* Wih_f  = (const float*)d_in[3];
  const float* Whh_f  = (const float*)d_in[4];
  const float* b_f    = (const float*)d_in[5];
  const float* Wih_b  = (const float*)d_in[6];
  const float* Whh_b  = (const float*)d_in[7];
  const float* b_b    = (const float*)d_in[8];
  const float* Wfc    = (const float*)d_in[9];
  const float* bfc    = (const float*)d_in[10];
  const float* start  = (const float*)d_in[11];
  const float* endt   = (const float*)d_in[12];
  const float* trans  = (const float*)d_in[13];

  float* out = (float*)d_out;
  float* ws = (float*)d_ws;
  unsigned short* preF = (unsigned short*)ws;                       // 16.7M bf16 (packed)
  unsigned short* preB = preF + (size_t)nBT * nG;                   // 16.7M bf16 (packed)
  unsigned short* hf   = preB + (size_t)nBT * nG;                   // 4.2M bf16
  unsigned short* hb   = hf + (size_t)nBT * nH;                     // 4.2M bf16
  float* em  = (float*)(hb + (size_t)nBT * nH);                     // 590K f32
  float* llh = em + (size_t)nBT * nC;                               // 64 f32
  unsigned short* wfb = (unsigned short*)(llh + 64);                // 393K bf16
  unsigned short* wbb = wfb + (size_t)nG * nE;                      // 393K bf16

  cvt_kernel<<<384, 256, 0, stream>>>(Wih_f, Wih_b, wfb, wbb, nG * nE / 8);
  proj_kernel<<<2048, 256, 0, stream>>>(x, wfb, wbb, b_f, b_b, preF, preB);
  lstm_kernel<<<8, 512, 0, stream>>>(preF, preB, Whh_f, Whh_b, hf, hb);
  em_kernel<<<1024, 256, 0, stream>>>(hf, hb, Wfc, bfc, em);
  crfvit_kernel<<<64, 128, 0, stream>>>(em, labels, amask, start, endt, trans, llh, out);
  loss_kernel<<<1, 64, 0, stream>>>(llh, out + nBT);
}

// Round 10
// 567.646 us; speedup vs baseline: 4.4981x; 1.6476x over previous
//
#include <hip/hip_runtime.h>
#include <hip/hip_bf16.h>
#include <math.h>

typedef __attribute__((ext_vector_type(8))) short short8;
typedef __attribute__((ext_vector_type(4))) float f32x4;

constexpr int nB = 64, nT = 512, nE = 768, nH = 128, nG = 512, nC = 18;
constexpr int nBT = nB * nT;

__device__ __forceinline__ float bf2f(unsigned short u) { return __uint_as_float(((unsigned int)u) << 16); }
__device__ __forceinline__ unsigned short f2bf(float f) {
  __hip_bfloat16 h = __float2bfloat16(f);
  return *reinterpret_cast<unsigned short*>(&h);
}
__device__ __forceinline__ float rlane(float v, int lane) {
  return __uint_as_float(__builtin_amdgcn_readlane(__float_as_uint(v), lane));
}
__device__ __forceinline__ float fast_sig(float x) {
  return __builtin_amdgcn_rcpf(1.0f + __builtin_amdgcn_exp2f(-1.44269504f * x));
}
__device__ __forceinline__ float fast_tanh(float x) {
  return 1.0f - 2.0f * __builtin_amdgcn_rcpf(1.0f + __builtin_amdgcn_exp2f(2.88539008f * x));
}

// ---------------- projection GEMM (bf16 MFMA): pre = x @ Wih^T + b ----------------
// Both x and Wih read as f32, converted to bf16 during LDS staging (no cvt pass).
__global__ __launch_bounds__(256) void proj_kernel(
    const float* __restrict__ x,
    const float* __restrict__ Wf, const float* __restrict__ Wb,
    const float* __restrict__ biasF, const float* __restrict__ biasB,
    unsigned short* __restrict__ Pf, unsigned short* __restrict__ Pb)
{
  const int bid = blockIdx.x;
  const int mt = bid & 255, sub = bid >> 8;
  const int dir = sub >> 2, nt = sub & 3;
  const float* W = dir ? Wb : Wf;
  const float* bias = dir ? biasB : biasF;
  unsigned short* P = dir ? Pb : Pf;
  const int m0 = mt * 128, n0 = nt * 128;

  __shared__ unsigned short As[128 * 40];
  __shared__ unsigned short Bs[128 * 40];
  const int tid = threadIdx.x;
  const int w = tid >> 6, lane = tid & 63, l15 = lane & 15, l4 = lane >> 4;
  const int wr = w >> 1, wc = w & 1;
  const int srow = tid >> 1, shalf = tid & 1;

  const float* srcA = x + (size_t)(m0 + srow) * nE + shalf * 16;
  const float* srcB = W + (size_t)(n0 + srow) * nE + shalf * 16;

  f32x4 acc[4][4];
#pragma unroll
  for (int i = 0; i < 4; ++i)
#pragma unroll
    for (int j = 0; j < 4; ++j) acc[i][j] = (f32x4){0.f, 0.f, 0.f, 0.f};

  for (int k0 = 0; k0 < nE; k0 += 32) {
    const float4 a0 = *(const float4*)(srcA + k0);
    const float4 a1 = *(const float4*)(srcA + k0 + 4);
    const float4 a2 = *(const float4*)(srcA + k0 + 8);
    const float4 a3 = *(const float4*)(srcA + k0 + 12);
    const float4 b0 = *(const float4*)(srcB + k0);
    const float4 b1 = *(const float4*)(srcB + k0 + 4);
    const float4 b2 = *(const float4*)(srcB + k0 + 8);
    const float4 b3 = *(const float4*)(srcB + k0 + 12);
    unsigned short ua[16] = {f2bf(a0.x), f2bf(a0.y), f2bf(a0.z), f2bf(a0.w),
                             f2bf(a1.x), f2bf(a1.y), f2bf(a1.z), f2bf(a1.w),
                             f2bf(a2.x), f2bf(a2.y), f2bf(a2.z), f2bf(a2.w),
                             f2bf(a3.x), f2bf(a3.y), f2bf(a3.z), f2bf(a3.w)};
    unsigned short ub[16] = {f2bf(b0.x), f2bf(b0.y), f2bf(b0.z), f2bf(b0.w),
                             f2bf(b1.x), f2bf(b1.y), f2bf(b1.z), f2bf(b1.w),
                             f2bf(b2.x), f2bf(b2.y), f2bf(b2.z), f2bf(b2.w),
                             f2bf(b3.x), f2bf(b3.y), f2bf(b3.z), f2bf(b3.w)};
    __syncthreads();
    *(float4*)&As[srow * 40 + shalf * 16] = *(float4*)&ua[0];
    *(float4*)&As[srow * 40 + shalf * 16 + 8] = *(float4*)&ua[8];
    *(float4*)&Bs[srow * 40 + shalf * 16] = *(float4*)&ub[0];
    *(float4*)&Bs[srow * 40 + shalf * 16 + 8] = *(float4*)&ub[8];
    __syncthreads();
    short8 af[4], bfr[4];
#pragma unroll
    for (int i = 0; i < 4; ++i) af[i] = *(const short8*)&As[(wr * 64 + i * 16 + l15) * 40 + l4 * 8];
#pragma unroll
    for (int j = 0; j < 4; ++j) bfr[j] = *(const short8*)&Bs[(wc * 64 + j * 16 + l15) * 40 + l4 * 8];
#pragma unroll
    for (int i = 0; i < 4; ++i)
#pragma unroll
      for (int j = 0; j < 4; ++j)
        acc[i][j] = __builtin_amdgcn_mfma_f32_16x16x32_bf16(af[i], bfr[j], acc[i][j], 0, 0, 0);
  }
  float bv[4];
#pragma unroll
  for (int j = 0; j < 4; ++j) bv[j] = bias[n0 + wc * 64 + j * 16 + l15];
#pragma unroll
  for (int i = 0; i < 4; ++i) {
#pragma unroll
    for (int j = 0; j < 4; ++j) {
      const int col = n0 + wc * 64 + j * 16 + l15;
#pragma unroll
      for (int r = 0; r < 4; ++r) {
        const int row = m0 + wr * 64 + i * 16 + l4 * 4 + r;
        P[(size_t)row * nG + col] = f2bf(acc[i][j][r] + bv[j]);
      }
    }
  }
}

// ---------------- MFMA LSTM v4 (proven 249 us): 32 blocks, 4 batches/block ----------------
__global__ __launch_bounds__(512, 1) void lstm_kernel(
    const unsigned short* __restrict__ Pf, const unsigned short* __restrict__ Pb,
    const float* __restrict__ WhhF, const float* __restrict__ WhhB,
    unsigned short* __restrict__ hf, unsigned short* __restrict__ hb)
{
  const int bid = blockIdx.x;
  const int dir = bid & 1, grp = bid >> 1;
  const int b0 = grp * 4;
  const unsigned short* pre = dir ? Pb : Pf;
  const float* Whh = dir ? WhhB : WhhF;
  unsigned short* hout = dir ? hb : hf;

  const int tid = threadIdx.x, w = tid >> 6, lane = tid & 63;
  const int l15 = lane & 15, l4 = lane >> 4;
  const int batch = l15 & 3, msel = l15 >> 2;
  const int cell = w * 16 + msel * 4 + l4;
  const int swz = batch * 40;

  __shared__ unsigned short h_lds[2 * 4 * 128];

  short8 Af[4][4];
#pragma unroll
  for (int m = 0; m < 4; ++m) {
    const int gp = w * 64 + m * 16 + l15;
    const int gorig = (gp & 3) * 128 + (gp >> 2);
#pragma unroll
    for (int kk = 0; kk < 4; ++kk) {
      const float* wp = Whh + (size_t)gorig * nH + kk * 32 + l4 * 8;
      const float4 v0 = *(const float4*)wp;
      const float4 v1 = *(const float4*)(wp + 4);
      unsigned short u[8] = {f2bf(v0.x), f2bf(v0.y), f2bf(v0.z), f2bf(v0.w),
                             f2bf(v1.x), f2bf(v1.y), f2bf(v1.z), f2bf(v1.w)};
      Af[m][kk] = *(short8*)u;
    }
  }
  for (int i = tid; i < 2 * 4 * 128; i += 512) h_lds[i] = 0;

  float c_state = 0.f;
  const unsigned short* pbase = pre + (size_t)(b0 + batch) * nT * nG + cell;

  unsigned short pA[4], pB[4];
  {
    const int tt0 = dir ? (nT - 1) : 0;
    const int tt1 = dir ? (nT - 2) : 1;
#pragma unroll
    for (int r = 0; r < 4; ++r) pA[r] = pbase[(size_t)tt0 * nG + r * 128];
#pragma unroll
    for (int r = 0; r < 4; ++r) pB[r] = pbase[(size_t)tt1 * nG + r * 128];
  }
  __syncthreads();

#define LSTM_STEP(RB, T, BUFC)                                                   \
  {                                                                              \
    const int ttime = dir ? (nT - 1 - (T)) : (T);                                \
    float pg[4];                                                                 \
    _Pragma("unroll")                                                            \
    for (int r = 0; r < 4; ++r) pg[r] = bf2f(BUFC[r]);                           \
    {                                                                            \
      const int tl = ((T) + 2 < nT) ? (T) + 2 : (T);                             \
      const int ttl = dir ? (nT - 1 - tl) : tl;                                  \
      _Pragma("unroll")                                                          \
      for (int r = 0; r < 4; ++r) BUFC[r] = pbase[(size_t)ttl * nG + r * 128];   \
    }                                                                            \
    short8 bfr[4];                                                               \
    _Pragma("unroll")                                                            \
    for (int kk = 0; kk < 4; ++kk) {                                             \
      const int idx = (RB) * 512 + batch * 128 + ((kk * 32 + l4 * 8) ^ swz);     \
      bfr[kk] = *(const short8*)&h_lds[idx];                                     \
    }                                                                            \
    f32x4 acc[4];                                                                \
    _Pragma("unroll")                                                            \
    for (int m = 0; m < 4; ++m) acc[m] = (f32x4){0.f, 0.f, 0.f, 0.f};            \
    _Pragma("unroll")                                                            \
    for (int kk = 0; kk < 4; ++kk)                                               \
      _Pragma("unroll")                                                          \
      for (int m = 0; m < 4; ++m)                                                \
        acc[m] = __builtin_amdgcn_mfma_f32_16x16x32_bf16(Af[m][kk], bfr[kk], acc[m], 0, 0, 0); \
    const float g0 = msel < 2 ? (msel == 0 ? acc[0][0] : acc[1][0]) : (msel == 2 ? acc[2][0] : acc[3][0]); \
    const float g1 = msel < 2 ? (msel == 0 ? acc[0][1] : acc[1][1]) : (msel == 2 ? acc[2][1] : acc[3][1]); \
    const float g2 = msel < 2 ? (msel == 0 ? acc[0][2] : acc[1][2]) : (msel == 2 ? acc[2][2] : acc[3][2]); \
    const float g3 = msel < 2 ? (msel == 0 ? acc[0][3] : acc[1][3]) : (msel == 2 ? acc[2][3] : acc[3][3]); \
    const float gi = g0 + pg[0], gf = g1 + pg[1], gg = g2 + pg[2], go = g3 + pg[3]; \
    c_state = fast_sig(gf) * c_state + fast_sig(gi) * fast_tanh(gg);             \
    const float hval = fast_sig(go) * fast_tanh(c_state);                        \
    const unsigned short hu = f2bf(hval);                                        \
    h_lds[((RB) ^ 1) * 512 + batch * 128 + (cell ^ swz)] = hu;                   \
    hout[((size_t)(b0 + batch) * nT + ttime) * nH + cell] = hu;                  \
    asm volatile("s_waitcnt lgkmcnt(0)" ::: "memory");                           \
    __builtin_amdgcn_sched_barrier(0);                                           \
    __builtin_amdgcn_s_barrier();                                                \
  }

  for (int t2 = 0; t2 < nT; t2 += 2) {
    LSTM_STEP(0, t2, pA)
    LSTM_STEP(1, t2 + 1, pB)
  }
#undef LSTM_STEP
}

// ---------------- emissions: em = [hf|hb] @ Wfc^T + bfc ----------------
__global__ __launch_bounds__(256) void em_kernel(
    const unsigned short* __restrict__ hf, const unsigned short* __restrict__ hb,
    const float* __restrict__ Wfc, const float* __restrict__ bfc,
    float* __restrict__ em)
{
  __shared__ float seq[32][260];
  __shared__ float Wf[18][260];
  const int tid = threadIdx.x;
  const int row0 = blockIdx.x * 32;
  for (int i = tid; i < 32 * 32; i += 256) {
    const int r = i >> 5, seg = i & 31;
    const unsigned short* src = (seg < 16) ? (hf + (size_t)(row0 + r) * nH + seg * 8)
                                           : (hb + (size_t)(row0 + r) * nH + (seg - 16) * 8);
    const float4 v = *(const float4*)src;
    const unsigned short* u = (const unsigned short*)&v;
#pragma unroll
    for (int k = 0; k < 8; ++k) seq[r][seg * 8 + k] = bf2f(u[k]);
  }
  for (int i = tid; i < nC * 256; i += 256) {
    const int cc = i >> 8, k = i & 255;
    Wf[cc][k] = Wfc[cc * 256 + k];
  }
  __syncthreads();
  for (int o = tid; o < 32 * nC; o += 256) {
    const int r = o / nC, cc = o - r * nC;
    float acc = bfc[cc];
    const float4* s4 = (const float4*)&seq[r][0];
    const float4* w4 = (const float4*)&Wf[cc][0];
#pragma unroll
    for (int q = 0; q < 64; ++q) {
      const float4 a = s4[q]; const float4 wv = w4[q];
      acc += a.x * wv.x + a.y * wv.y + a.z * wv.z + a.w * wv.w;
    }
    em[(size_t)(row0 + r) * nC + cc] = acc;
  }
}

// ---------------- fused CRF + Viterbi (register recurrences, CRF in log2 domain) -------
__global__ __launch_bounds__(128) void crfvit_kernel(
    const float* __restrict__ em, const int* __restrict__ labels,
    const int* __restrict__ mask, const float* __restrict__ start,
    const float* __restrict__ endt, const float* __restrict__ trans,
    float* __restrict__ llh, float* __restrict__ out_path)
{
  constexpr float K2 = 1.44269504088896f;   // log2(e)
  constexpr float LN2 = 0.69314718055995f;
  const int b = blockIdx.x; const int tid = threadIdx.x;
  __shared__ float tr[nC * nC];
  __shared__ unsigned char bp[(nT - 1) * nC];
  __shared__ unsigned char path[nT];
  for (int i = tid; i < nC * nC; i += 128) tr[i] = trans[i];
  __syncthreads();
  const float* eb = em + (size_t)b * nT * nC;

#define MAX18(c) fmaxf(fmaxf(fmaxf(fmaxf(fmaxf(c[0], c[1]), c[2]), fmaxf(fmaxf(c[3], c[4]), c[5])),           \
                             fmaxf(fmaxf(fmaxf(c[6], c[7]), c[8]), fmaxf(fmaxf(c[9], c[10]), c[11]))),        \
                       fmaxf(fmaxf(fmaxf(c[12], c[13]), c[14]), fmaxf(fmaxf(c[15], c[16]), c[17])))

  if (tid < 64) {
    // ------- CRF wave: alpha in registers (log2 domain), readlane broadcast -------
    const int l = tid;
    const int lc = l < nC ? l : nC - 1;
    const int* tg = labels + (size_t)b * nT;
    const int* mk = mask + (size_t)b * nT;

    // numerator (natural units)
    float np = 0.f; int cnt = 0;
    for (int t = l; t < nT; t += 64) {
      const int tag = tg[t];
      const float e = eb[(size_t)t * nC + tag];
      if (t == 0) np += start[tag] + e;
      else np += (float)mk[t] * (e + tr[tg[t - 1] * nC + tag]);
      cnt += mk[t];
    }
#pragma unroll
    for (int off = 32; off; off >>= 1) { np += __shfl_xor(np, off); cnt += __shfl_xor(cnt, off); }
    const float num = np + endt[tg[cnt - 1]];

    // transition column, pre-scaled to log2 domain
    float trc[nC];
#pragma unroll
    for (int i = 0; i < nC; ++i) trc[i] = tr[i * nC + lc] * K2;

    float alpha2 = (start[lc] + eb[lc]) * K2;
    float eA = eb[1 * nC + lc] * K2;
    float eB = eb[2 * nC + lc] * K2;
    float eC = eb[3 * nC + lc] * K2;
    for (int tk = 0; tk < 8; ++tk) {
      const unsigned long long mb = __ballot(mk[tk * 64 + l] != 0);
      for (int tt = (tk == 0 ? 1 : 0); tt < 64; ++tt) {
        const int t = tk * 64 + tt;
        const float ecur = eA; eA = eB; eB = eC;
        const int tl = t + 3 < nT ? t + 3 : nT - 1;
        eC = eb[(size_t)tl * nC + lc] * K2;
        float cand[nC];
#pragma unroll
        for (int i = 0; i < nC; ++i) cand[i] = rlane(alpha2, i) + trc[i];
        const float m = MAX18(cand);
        float s = 0.f;
#pragma unroll
        for (int i = 0; i < nC; ++i) s += __builtin_amdgcn_exp2f(cand[i] - m);
        const float anew = m + __builtin_amdgcn_logf(s) + ecur;
        alpha2 = ((mb >> tt) & 1) ? anew : alpha2;
      }
    }
    const float v = (l < nC) ? (alpha2 + endt[l] * K2) : -3.0e38f;
    float m = v;
#pragma unroll
    for (int off = 32; off; off >>= 1) m = fmaxf(m, __shfl_xor(m, off));
    float s = (l < nC) ? __builtin_amdgcn_exp2f(v - m) : 0.f;
#pragma unroll
    for (int off = 32; off; off >>= 1) s += __shfl_xor(s, off);
    if (l == 0) llh[b] = num - (m + __builtin_amdgcn_logf(s)) * LN2;
  } else {
    // ------- Viterbi wave: score in registers (natural units) -------
    const int l = tid - 64;
    const int lc = l < nC ? l : nC - 1;
    float trc[nC];
#pragma unroll
    for (int i = 0; i < nC; ++i) trc[i] = tr[i * nC + lc];

    float score_r = start[lc] + eb[lc];
    float eA = eb[1 * nC + lc];
    float eB = eb[2 * nC + lc];
    float eC = eb[3 * nC + lc];
    for (int t = 1; t < nT; ++t) {
      const float ecur = eA; eA = eB; eB = eC;
      const int tl = t + 3 < nT ? t + 3 : nT - 1;
      eC = eb[(size_t)tl * nC + lc];
      float cand[nC];
#pragma unroll
      for (int i = 0; i < nC; ++i) cand[i] = rlane(score_r, i) + trc[i];
      const float m = MAX18(cand);
      int sel[nC];
#pragma unroll
      for (int i = 0; i < nC; ++i) sel[i] = (cand[i] == m) ? i : 63;
      int arg = sel[0];
#pragma unroll
      for (int i = 1; i < nC; ++i) arg = min(arg, sel[i]);
      score_r = m + ecur;
      if (l < nC) bp[(t - 1) * nC + l] = (unsigned char)arg;
    }
    if (l == 0) {
      float mm = -3.0e38f; int last = 0;
      for (int i = 0; i < nC; ++i) {
        const float v = rlane(score_r, i) + endt[i];
        if (v > mm) { mm = v; last = i; }
      }
      path[nT - 1] = (unsigned char)last;
      int cur = last;
      for (int t = nT - 2; t >= 0; --t) { cur = bp[t * nC + cur]; path[t] = (unsigned char)cur; }
    }
    asm volatile("s_waitcnt lgkmcnt(0)" ::: "memory");
    __builtin_amdgcn_wave_barrier();
    for (int t = l; t < nT; t += 64) out_path[(size_t)b * nT + t] = (float)(path[t] + 1);
  }
#undef MAX18
}

// ---------------- loss finalize ----------------
__global__ __launch_bounds__(64) void loss_kernel(const float* __restrict__ llh, float* __restrict__ out)
{
  const int l = threadIdx.x;
  float v = llh[l];
#pragma unroll
  for (int off = 32; off; off >>= 1) v += __shfl_xor(v, off);
  if (l == 0) out[0] = -v / (float)nB;
}

extern "C" void kernel_launch(void* const* d_in, const int* in_sizes, int n_in,
                              void* d_out, int out_size, void* d_ws, size_t ws_size,
                              hipStream_t stream)
{
  const float* x      = (const float*)d_in[0];
  const int*   amask  = (const int*)d_in[1];
  const int*   labels = (const int*)d_in[2];
  const float* Wih_f  = (const float*)d_in[3];
  const float* Whh_f  = (const float*)d_in[4];
  const float* b_f    = (const float*)d_in[5];
  const float* Wih_b  = (const float*)d_in[6];
  const float* Whh_b  = (const float*)d_in[7];
  const float* b_b    = (const float*)d_in[8];
  const float* Wfc    = (const float*)d_in[9];
  const float* bfc    = (const float*)d_in[10];
  const float* start  = (const float*)d_in[11];
  const float* endt   = (const float*)d_in[12];
  const float* trans  = (const float*)d_in[13];

  float* out = (float*)d_out;
  float* ws = (float*)d_ws;
  unsigned short* preF = (unsigned short*)ws;                       // 16.7M bf16
  unsigned short* preB = preF + (size_t)nBT * nG;                   // 16.7M bf16
  unsigned short* hf   = preB + (size_t)nBT * nG;                   // 4.2M bf16
  unsigned short* hb   = hf + (size_t)nBT * nH;                     // 4.2M bf16
  float* em  = (float*)(hb + (size_t)nBT * nH);                     // 590K f32
  float* llh = em + (size_t)nBT * nC;                               // 64 f32

  proj_kernel<<<2048, 256, 0, stream>>>(x, Wih_f, Wih_b, b_f, b_b, preF, preB);
  lstm_kernel<<<32, 512, 0, stream>>>(preF, preB, Whh_f, Whh_b, hf, hb);
  em_kernel<<<1024, 256, 0, stream>>>(hf, hb, Wfc, bfc, em);
  crfvit_kernel<<<64, 128, 0, stream>>>(em, labels, amask, start, endt, trans, llh, out);
  loss_kernel<<<1, 64, 0, stream>>>(llh, out + nBT);
}

// Round 11
// 542.405 us; speedup vs baseline: 4.7074x; 1.0465x over previous
//
#include <hip/hip_runtime.h>
#include <hip/hip_bf16.h>
#include <math.h>

typedef __attribute__((ext_vector_type(8))) short short8;
typedef __attribute__((ext_vector_type(4))) float f32x4;

constexpr int nB = 64, nT = 512, nE = 768, nH = 128, nG = 512, nC = 18;
constexpr int nBT = nB * nT;

__device__ __forceinline__ float bf2f(unsigned short u) { return __uint_as_float(((unsigned int)u) << 16); }
__device__ __forceinline__ unsigned short f2bf(float f) {
  __hip_bfloat16 h = __float2bfloat16(f);
  return *reinterpret_cast<unsigned short*>(&h);
}
__device__ __forceinline__ float rlane(float v, int lane) {
  return __uint_as_float(__builtin_amdgcn_readlane(__float_as_uint(v), lane));
}
__device__ __forceinline__ float fast_sig(float x) {
  return __builtin_amdgcn_rcpf(1.0f + __builtin_amdgcn_exp2f(-1.44269504f * x));
}
__device__ __forceinline__ float fast_tanh(float x) {
  return 1.0f - 2.0f * __builtin_amdgcn_rcpf(1.0f + __builtin_amdgcn_exp2f(2.88539008f * x));
}

// ---------------- f32 -> bf16 convert: x ----------------
__global__ __launch_bounds__(256) void cvt_kernel(const float* __restrict__ in,
                                                  unsigned short* __restrict__ out, int n8) {
  int i = blockIdx.x * blockDim.x + threadIdx.x;
  const int stride = gridDim.x * blockDim.x;
  for (; i < n8; i += stride) {
    const float4 a = ((const float4*)in)[(size_t)i * 2];
    const float4 b = ((const float4*)in)[(size_t)i * 2 + 1];
    unsigned short u[8] = {f2bf(a.x), f2bf(a.y), f2bf(a.z), f2bf(a.w),
                           f2bf(b.x), f2bf(b.y), f2bf(b.z), f2bf(b.w)};
    ((float4*)out)[i] = *(float4*)u;
  }
}

// ---------------- f32 -> bf16 convert: both Wih in one launch ----------------
__global__ __launch_bounds__(256) void cvtw_kernel(const float* __restrict__ inF,
                                                   const float* __restrict__ inB,
                                                   unsigned short* __restrict__ outF,
                                                   unsigned short* __restrict__ outB, int n8) {
  const int half = gridDim.x >> 1;
  const float* in = (blockIdx.x < half) ? inF : inB;
  unsigned short* out = (blockIdx.x < half) ? outF : outB;
  const int bid = (blockIdx.x < half) ? blockIdx.x : blockIdx.x - half;
  int i = bid * blockDim.x + threadIdx.x;
  const int stride = half * blockDim.x;
  for (; i < n8; i += stride) {
    const float4 a = ((const float4*)in)[(size_t)i * 2];
    const float4 b = ((const float4*)in)[(size_t)i * 2 + 1];
    unsigned short u[8] = {f2bf(a.x), f2bf(a.y), f2bf(a.z), f2bf(a.w),
                           f2bf(b.x), f2bf(b.y), f2bf(b.z), f2bf(b.w)};
    ((float4*)out)[i] = *(float4*)u;
  }
}

// ---------------- projection GEMM (bf16 MFMA, bf16 inputs): pre = x @ Wih^T + b --------
__global__ __launch_bounds__(256) void proj_kernel(
    const unsigned short* __restrict__ xbf,
    const unsigned short* __restrict__ wfb, const unsigned short* __restrict__ wbb,
    const float* __restrict__ biasF, const float* __restrict__ biasB,
    unsigned short* __restrict__ Pf, unsigned short* __restrict__ Pb)
{
  const int bid = blockIdx.x;
  const int mt = bid & 255, sub = bid >> 8;
  const int dir = sub >> 2, nt = sub & 3;
  const unsigned short* W = dir ? wbb : wfb;
  const float* bias = dir ? biasB : biasF;
  unsigned short* P = dir ? Pb : Pf;
  const int m0 = mt * 128, n0 = nt * 128;

  __shared__ unsigned short As[128 * 40];
  __shared__ unsigned short Bs[128 * 40];
  const int tid = threadIdx.x;
  const int w = tid >> 6, lane = tid & 63, l15 = lane & 15, l4 = lane >> 4;
  const int wr = w >> 1, wc = w & 1;
  const int srow = tid >> 1, shalf = tid & 1;

  const unsigned short* srcA = xbf + (size_t)(m0 + srow) * nE + shalf * 16;
  const unsigned short* srcB = W + (size_t)(n0 + srow) * nE + shalf * 16;

  f32x4 acc[4][4];
#pragma unroll
  for (int i = 0; i < 4; ++i)
#pragma unroll
    for (int j = 0; j < 4; ++j) acc[i][j] = (f32x4){0.f, 0.f, 0.f, 0.f};

  for (int k0 = 0; k0 < nE; k0 += 32) {
    const float4 a0 = *(const float4*)(srcA + k0);
    const float4 a1 = *(const float4*)(srcA + k0 + 8);
    const float4 b0 = *(const float4*)(srcB + k0);
    const float4 b1 = *(const float4*)(srcB + k0 + 8);
    __syncthreads();
    *(float4*)&As[srow * 40 + shalf * 16] = a0;
    *(float4*)&As[srow * 40 + shalf * 16 + 8] = a1;
    *(float4*)&Bs[srow * 40 + shalf * 16] = b0;
    *(float4*)&Bs[srow * 40 + shalf * 16 + 8] = b1;
    __syncthreads();
    short8 af[4], bfr[4];
#pragma unroll
    for (int i = 0; i < 4; ++i) af[i] = *(const short8*)&As[(wr * 64 + i * 16 + l15) * 40 + l4 * 8];
#pragma unroll
    for (int j = 0; j < 4; ++j) bfr[j] = *(const short8*)&Bs[(wc * 64 + j * 16 + l15) * 40 + l4 * 8];
#pragma unroll
    for (int i = 0; i < 4; ++i)
#pragma unroll
      for (int j = 0; j < 4; ++j)
        acc[i][j] = __builtin_amdgcn_mfma_f32_16x16x32_bf16(af[i], bfr[j], acc[i][j], 0, 0, 0);
  }
  float bv[4];
#pragma unroll
  for (int j = 0; j < 4; ++j) bv[j] = bias[n0 + wc * 64 + j * 16 + l15];
#pragma unroll
  for (int i = 0; i < 4; ++i) {
#pragma unroll
    for (int j = 0; j < 4; ++j) {
      const int col = n0 + wc * 64 + j * 16 + l15;
#pragma unroll
      for (int r = 0; r < 4; ++r) {
        const int row = m0 + wr * 64 + i * 16 + l4 * 4 + r;
        P[(size_t)row * nG + col] = f2bf(acc[i][j][r] + bv[j]);
      }
    }
  }
}

// ---------------- MFMA LSTM v4 (proven 249 us): 32 blocks, 4 batches/block ----------------
__global__ __launch_bounds__(512, 1) void lstm_kernel(
    const unsigned short* __restrict__ Pf, const unsigned short* __restrict__ Pb,
    const float* __restrict__ WhhF, const float* __restrict__ WhhB,
    unsigned short* __restrict__ hf, unsigned short* __restrict__ hb)
{
  const int bid = blockIdx.x;
  const int dir = bid & 1, grp = bid >> 1;
  const int b0 = grp * 4;
  const unsigned short* pre = dir ? Pb : Pf;
  const float* Whh = dir ? WhhB : WhhF;
  unsigned short* hout = dir ? hb : hf;

  const int tid = threadIdx.x, w = tid >> 6, lane = tid & 63;
  const int l15 = lane & 15, l4 = lane >> 4;
  const int batch = l15 & 3, msel = l15 >> 2;
  const int cell = w * 16 + msel * 4 + l4;
  const int swz = batch * 40;

  __shared__ unsigned short h_lds[2 * 4 * 128];

  short8 Af[4][4];
#pragma unroll
  for (int m = 0; m < 4; ++m) {
    const int gp = w * 64 + m * 16 + l15;
    const int gorig = (gp & 3) * 128 + (gp >> 2);
#pragma unroll
    for (int kk = 0; kk < 4; ++kk) {
      const float* wp = Whh + (size_t)gorig * nH + kk * 32 + l4 * 8;
      const float4 v0 = *(const float4*)wp;
      const float4 v1 = *(const float4*)(wp + 4);
      unsigned short u[8] = {f2bf(v0.x), f2bf(v0.y), f2bf(v0.z), f2bf(v0.w),
                             f2bf(v1.x), f2bf(v1.y), f2bf(v1.z), f2bf(v1.w)};
      Af[m][kk] = *(short8*)u;
    }
  }
  for (int i = tid; i < 2 * 4 * 128; i += 512) h_lds[i] = 0;

  float c_state = 0.f;
  const unsigned short* pbase = pre + (size_t)(b0 + batch) * nT * nG + cell;

  unsigned short pA[4], pB[4];
  {
    const int tt0 = dir ? (nT - 1) : 0;
    const int tt1 = dir ? (nT - 2) : 1;
#pragma unroll
    for (int r = 0; r < 4; ++r) pA[r] = pbase[(size_t)tt0 * nG + r * 128];
#pragma unroll
    for (int r = 0; r < 4; ++r) pB[r] = pbase[(size_t)tt1 * nG + r * 128];
  }
  __syncthreads();

#define LSTM_STEP(RB, T, BUFC)                                                   \
  {                                                                              \
    const int ttime = dir ? (nT - 1 - (T)) : (T);                                \
    float pg[4];                                                                 \
    _Pragma("unroll")                                                            \
    for (int r = 0; r < 4; ++r) pg[r] = bf2f(BUFC[r]);                           \
    {                                                                            \
      const int tl = ((T) + 2 < nT) ? (T) + 2 : (T);                             \
      const int ttl = dir ? (nT - 1 - tl) : tl;                                  \
      _Pragma("unroll")                                                          \
      for (int r = 0; r < 4; ++r) BUFC[r] = pbase[(size_t)ttl * nG + r * 128];   \
    }                                                                            \
    short8 bfr[4];                                                               \
    _Pragma("unroll")                                                            \
    for (int kk = 0; kk < 4; ++kk) {                                             \
      const int idx = (RB) * 512 + batch * 128 + ((kk * 32 + l4 * 8) ^ swz);     \
      bfr[kk] = *(const short8*)&h_lds[idx];                                     \
    }                                                                            \
    f32x4 acc[4];                                                                \
    _Pragma("unroll")                                                            \
    for (int m = 0; m < 4; ++m) acc[m] = (f32x4){0.f, 0.f, 0.f, 0.f};            \
    _Pragma("unroll")                                                            \
    for (int kk = 0; kk < 4; ++kk)                                               \
      _Pragma("unroll")                                                          \
      for (int m = 0; m < 4; ++m)                                                \
        acc[m] = __builtin_amdgcn_mfma_f32_16x16x32_bf16(Af[m][kk], bfr[kk], acc[m], 0, 0, 0); \
    const float g0 = msel < 2 ? (msel == 0 ? acc[0][0] : acc[1][0]) : (msel == 2 ? acc[2][0] : acc[3][0]); \
    const float g1 = msel < 2 ? (msel == 0 ? acc[0][1] : acc[1][1]) : (msel == 2 ? acc[2][1] : acc[3][1]); \
    const float g2 = msel < 2 ? (msel == 0 ? acc[0][2] : acc[1][2]) : (msel == 2 ? acc[2][2] : acc[3][2]); \
    const float g3 = msel < 2 ? (msel == 0 ? acc[0][3] : acc[1][3]) : (msel == 2 ? acc[2][3] : acc[3][3]); \
    const float gi = g0 + pg[0], gf = g1 + pg[1], gg = g2 + pg[2], go = g3 + pg[3]; \
    c_state = fast_sig(gf) * c_state + fast_sig(gi) * fast_tanh(gg);             \
    const float hval = fast_sig(go) * fast_tanh(c_state);                        \
    const unsigned short hu = f2bf(hval);                                        \
    h_lds[((RB) ^ 1) * 512 + batch * 128 + (cell ^ swz)] = hu;                   \
    hout[((size_t)(b0 + batch) * nT + ttime) * nH + cell] = hu;                  \
    asm volatile("s_waitcnt lgkmcnt(0)" ::: "memory");                           \
    __builtin_amdgcn_sched_barrier(0);                                           \
    __builtin_amdgcn_s_barrier();                                                \
  }

  for (int t2 = 0; t2 < nT; t2 += 2) {
    LSTM_STEP(0, t2, pA)
    LSTM_STEP(1, t2 + 1, pB)
  }
#undef LSTM_STEP
}

// ---------------- emissions: em = [hf|hb] @ Wfc^T + bfc ----------------
__global__ __launch_bounds__(256) void em_kernel(
    const unsigned short* __restrict__ hf, const unsigned short* __restrict__ hb,
    const float* __restrict__ Wfc, const float* __restrict__ bfc,
    float* __restrict__ em)
{
  __shared__ float seq[32][260];
  __shared__ float Wf[18][260];
  const int tid = threadIdx.x;
  const int row0 = blockIdx.x * 32;
  for (int i = tid; i < 32 * 32; i += 256) {
    const int r = i >> 5, seg = i & 31;
    const unsigned short* src = (seg < 16) ? (hf + (size_t)(row0 + r) * nH + seg * 8)
                                           : (hb + (size_t)(row0 + r) * nH + (seg - 16) * 8);
    const float4 v = *(const float4*)src;
    const unsigned short* u = (const unsigned short*)&v;
#pragma unroll
    for (int k = 0; k < 8; ++k) seq[r][seg * 8 + k] = bf2f(u[k]);
  }
  for (int i = tid; i < nC * 256; i += 256) {
    const int cc = i >> 8, k = i & 255;
    Wf[cc][k] = Wfc[cc * 256 + k];
  }
  __syncthreads();
  for (int o = tid; o < 32 * nC; o += 256) {
    const int r = o / nC, cc = o - r * nC;
    float acc = bfc[cc];
    const float4* s4 = (const float4*)&seq[r][0];
    const float4* w4 = (const float4*)&Wf[cc][0];
#pragma unroll
    for (int q = 0; q < 64; ++q) {
      const float4 a = s4[q]; const float4 wv = w4[q];
      acc += a.x * wv.x + a.y * wv.y + a.z * wv.z + a.w * wv.w;
    }
    em[(size_t)(row0 + r) * nC + cc] = acc;
  }
}

// ---------------- CRF + Viterbi v3: role-split blocks, 8-deep static em prefetch -------
// 128 blocks x 64 threads: block = (batch, role). role 0 = CRF, role 1 = Viterbi.
// em values consumed per serial step come from a ping-pong pair of 8-register
// buffers (fully unrolled static indexing), loaded one full chunk (~8 steps) ahead.
__global__ __launch_bounds__(64) void crfvit_kernel(
    const float* __restrict__ em, const int* __restrict__ labels,
    const int* __restrict__ mask, const float* __restrict__ start,
    const float* __restrict__ endt, const float* __restrict__ trans,
    float* __restrict__ llh, float* __restrict__ out_path)
{
  constexpr float K2 = 1.44269504088896f;
  constexpr float LN2 = 0.69314718055995f;
  const int b = blockIdx.x >> 1, role = blockIdx.x & 1;
  const int l = threadIdx.x;
  __shared__ float tr[nC * nC];
  __shared__ unsigned char bp[(nT - 1) * nC];
  __shared__ unsigned char path[nT];
  for (int i = l; i < nC * nC; i += 64) tr[i] = trans[i];
  __syncthreads();
  const float* eb = em + (size_t)b * nT * nC;
  const int lc = l < nC ? l : nC - 1;

#define MAX18(c) fmaxf(fmaxf(fmaxf(fmaxf(fmaxf(c[0], c[1]), c[2]), fmaxf(fmaxf(c[3], c[4]), c[5])),           \
                             fmaxf(fmaxf(fmaxf(c[6], c[7]), c[8]), fmaxf(fmaxf(c[9], c[10]), c[11]))),        \
                       fmaxf(fmaxf(fmaxf(c[12], c[13]), c[14]), fmaxf(fmaxf(c[15], c[16]), c[17])))
#define TREESUM(ex, s) {                                                          \
    const float p0 = ex[0] + ex[1], p1 = ex[2] + ex[3], p2 = ex[4] + ex[5];       \
    const float p3 = ex[6] + ex[7], p4 = ex[8] + ex[9], p5 = ex[10] + ex[11];     \
    const float p6 = ex[12] + ex[13], p7 = ex[14] + ex[15], p8 = ex[16] + ex[17]; \
    const float q0 = p0 + p1, q1 = p2 + p3, q2 = p4 + p5, q3 = p6 + p7;           \
    s = ((q0 + q1) + (q2 + q3)) + p8;                                             \
  }

  if (role == 0) {
    // ------- CRF -------
    const int* tg = labels + (size_t)b * nT;
    const int* mk = mask + (size_t)b * nT;

    float np = 0.f; int cnt = 0;
    for (int t = l; t < nT; t += 64) {
      const int tag = tg[t];
      const float e = eb[(size_t)t * nC + tag];
      if (t == 0) np += start[tag] + e;
      else np += (float)mk[t] * (e + tr[tg[t - 1] * nC + tag]);
      cnt += mk[t];
    }
#pragma unroll
    for (int off = 32; off; off >>= 1) { np += __shfl_xor(np, off); cnt += __shfl_xor(cnt, off); }
    const float num = np + endt[tg[cnt - 1]];

    float trc[nC];
#pragma unroll
    for (int i = 0; i < nC; ++i) trc[i] = tr[i * nC + lc] * K2;

    float alpha2 = (start[lc] + eb[lc]) * K2;
    float ec[8], en[8];
#pragma unroll
    for (int j = 0; j < 8; ++j) ec[j] = eb[j * nC + lc] * K2;
#pragma unroll
    for (int j = 0; j < 8; ++j) en[j] = eb[(8 + j) * nC + lc] * K2;
    unsigned long long mb = __ballot(mk[l] != 0);

#define CRF_STEP(T, E) {                                                          \
      float cand[nC];                                                             \
      _Pragma("unroll")                                                           \
      for (int i = 0; i < nC; ++i) cand[i] = rlane(alpha2, i) + trc[i];           \
      const float m = MAX18(cand);                                                \
      float ex[nC];                                                               \
      _Pragma("unroll")                                                           \
      for (int i = 0; i < nC; ++i) ex[i] = __builtin_amdgcn_exp2f(cand[i] - m);   \
      float s; TREESUM(ex, s);                                                    \
      const float anew = m + __builtin_amdgcn_logf(s) + (E);                      \
      alpha2 = ((mb >> ((T) & 63)) & 1) ? anew : alpha2;                          \
    }

#pragma unroll
    for (int j = 1; j < 8; ++j) CRF_STEP(j, ec[j])
    for (int c = 1; c < 64; ++c) {
#pragma unroll
      for (int j = 0; j < 8; ++j) ec[j] = en[j];
      const int tn = (c < 63) ? (c + 1) * 8 : 504;
#pragma unroll
      for (int j = 0; j < 8; ++j) en[j] = eb[(size_t)(tn + j) * nC + lc] * K2;
      if ((c & 7) == 0) mb = __ballot(mk[c * 8 + l] != 0);
#pragma unroll
      for (int j = 0; j < 8; ++j) CRF_STEP(c * 8 + j, ec[j])
    }
#undef CRF_STEP
    const float v = (l < nC) ? (alpha2 + endt[l] * K2) : -3.0e38f;
    float m = v;
#pragma unroll
    for (int off = 32; off; off >>= 1) m = fmaxf(m, __shfl_xor(m, off));
    float s = (l < nC) ? __builtin_amdgcn_exp2f(v - m) : 0.f;
#pragma unroll
    for (int off = 32; off; off >>= 1) s += __shfl_xor(s, off);
    if (l == 0) llh[b] = num - (m + __builtin_amdgcn_logf(s)) * LN2;
  } else {
    // ------- Viterbi -------
    float trc[nC];
#pragma unroll
    for (int i = 0; i < nC; ++i) trc[i] = tr[i * nC + lc];

    float score_r = start[lc] + eb[lc];
    float ec[8], en[8];
#pragma unroll
    for (int j = 0; j < 8; ++j) ec[j] = eb[j * nC + lc];
#pragma unroll
    for (int j = 0; j < 8; ++j) en[j] = eb[(8 + j) * nC + lc];

#define VIT_STEP(T, E) {                                                          \
      float cand[nC];                                                             \
      _Pragma("unroll")                                                           \
      for (int i = 0; i < nC; ++i) cand[i] = rlane(score_r, i) + trc[i];          \
      const float m = MAX18(cand);                                                \
      int sel[nC];                                                                \
      _Pragma("unroll")                                                           \
      for (int i = 0; i < nC; ++i) sel[i] = (cand[i] == m) ? i : 63;              \
      int arg = sel[0];                                                           \
      _Pragma("unroll")                                                           \
      for (int i = 1; i < nC; ++i) arg = min(arg, sel[i]);                        \
      score_r = m + (E);                                                          \
      if (l < nC) bp[((T) - 1) * nC + l] = (unsigned char)arg;                    \
    }

#pragma unroll
    for (int j = 1; j < 8; ++j) VIT_STEP(j, ec[j])
    for (int c = 1; c < 64; ++c) {
#pragma unroll
      for (int j = 0; j < 8; ++j) ec[j] = en[j];
      const int tn = (c < 63) ? (c + 1) * 8 : 504;
#pragma unroll
      for (int j = 0; j < 8; ++j) en[j] = eb[(size_t)(tn + j) * nC + lc];
#pragma unroll
      for (int j = 0; j < 8; ++j) VIT_STEP(c * 8 + j, ec[j])
    }
#undef VIT_STEP
    if (l == 0) {
      float mm = -3.0e38f; int last = 0;
      for (int i = 0; i < nC; ++i) {
        const float v = rlane(score_r, i) + endt[i];
        if (v > mm) { mm = v; last = i; }
      }
      path[nT - 1] = (unsigned char)last;
      int cur = last;
      for (int t = nT - 2; t >= 0; --t) { cur = bp[t * nC + cur]; path[t] = (unsigned char)cur; }
    }
    asm volatile("s_waitcnt lgkmcnt(0)" ::: "memory");
    __builtin_amdgcn_wave_barrier();
    for (int t = l; t < nT; t += 64) out_path[(size_t)b * nT + t] = (float)(path[t] + 1);
  }
#undef MAX18
#undef TREESUM
}

// ---------------- loss finalize ----------------
__global__ __launch_bounds__(64) void loss_kernel(const float* __restrict__ llh, float* __restrict__ out)
{
  const int l = threadIdx.x;
  float v = llh[l];
#pragma unroll
  for (int off = 32; off; off >>= 1) v += __shfl_xor(v, off);
  if (l == 0) out[0] = -v / (float)nB;
}

extern "C" void kernel_launch(void* const* d_in, const int* in_sizes, int n_in,
                              void* d_out, int out_size, void* d_ws, size_t ws_size,
                              hipStream_t stream)
{
  const float* x      = (const float*)d_in[0];
  const int*   amask  = (const int*)d_in[1];
  const int*   labels = (const int*)d_in[2];
  const float* Wih_f  = (const float*)d_in[3];
  const float* Whh_f  = (const float*)d_in[4];
  const float* b_f    = (const float*)d_in[5];
  const float* Wih_b  = (const float*)d_in[6];
  const float* Whh_b  = (const float*)d_in[7];
  const float* b_b    = (const float*)d_in[8];
  const float* Wfc    = (const float*)d_in[9];
  const float* bfc    = (const float*)d_in[10];
  const float* start  = (const float*)d_in[11];
  const float* endt   = (const float*)d_in[12];
  const float* trans  = (const float*)d_in[13];

  float* out = (float*)d_out;
  float* ws = (float*)d_ws;
  unsigned short* preF = (unsigned short*)ws;                       // 16.7M bf16
  unsigned short* preB = preF + (size_t)nBT * nG;                   // 16.7M bf16
  unsigned short* hf   = preB + (size_t)nBT * nG;                   // 4.2M bf16
  unsigned short* hb   = hf + (size_t)nBT * nH;                     // 4.2M bf16
  float* em  = (float*)(hb + (size_t)nBT * nH);                     // 590K f32
  float* llh = em + (size_t)nBT * nC;                               // 64 f32
  unsigned short* xbf = (unsigned short*)(llh + 64);                // 25.2M bf16
  unsigned short* wfb = xbf + (size_t)nBT * nE;                     // 393K bf16
  unsigned short* wbb = wfb + (size_t)nG * nE;                      // 393K bf16

  cvt_kernel<<<4096, 256, 0, stream>>>(x, xbf, nBT * nE / 8);
  cvtw_kernel<<<384, 256, 0, stream>>>(Wih_f, Wih_b, wfb, wbb, nG * nE / 8);
  proj_kernel<<<2048, 256, 0, stream>>>(xbf, wfb, wbb, b_f, b_b, preF, preB);
  lstm_kernel<<<32, 512, 0, stream>>>(preF, preB, Whh_f, Whh_b, hf, hb);
  em_kernel<<<1024, 256, 0, stream>>>(hf, hb, Wfc, bfc, em);
  crfvit_kernel<<<128, 64, 0, stream>>>(em, labels, amask, start, endt, trans, llh, out);
  loss_kernel<<<1, 64, 0, stream>>>(llh, out + nBT);
}